// Round 1
// baseline (628.832 us; speedup 1.0000x reference)
//
#include <hip/hip_runtime.h>

#define N_NODES 50000
#define N_EDGES 640000
#define TOT_E (N_EDGES + N_NODES)
#define NBLK 196            // ceil(N_NODES/256)
#define NG 128
#define DFFN 512
#define NCLS 10
#define NEG 0.2f

// ---------------- CSR build ----------------
__global__ void count_kernel(const int* __restrict__ ei, int* __restrict__ deg) {
  int i = blockIdx.x * blockDim.x + threadIdx.x;
  if (i >= TOT_E) return;
  int d = (i < N_EDGES) ? ei[N_EDGES + i] : (i - N_EDGES);
  atomicAdd(&deg[d], 1);
}

__global__ void scanA(const int* __restrict__ deg, int* __restrict__ rowptr,
                      int* __restrict__ bsum) {
  __shared__ int s[256];
  int t = threadIdx.x;
  int i = blockIdx.x * 256 + t;
  int v = (i < N_NODES) ? deg[i] : 0;
  s[t] = v; __syncthreads();
  for (int off = 1; off < 256; off <<= 1) {
    int tmp = (t >= off) ? s[t - off] : 0;
    __syncthreads();
    s[t] += tmp;
    __syncthreads();
  }
  if (i < N_NODES) rowptr[i] = s[t] - v;   // exclusive, block-local
  if (t == 255) bsum[blockIdx.x] = s[255];
}

__global__ void scanB(const int* __restrict__ bsum, int* __restrict__ bofs) {
  __shared__ int s[256];
  int t = threadIdx.x;
  int v = (t < NBLK) ? bsum[t] : 0;
  s[t] = v; __syncthreads();
  for (int off = 1; off < 256; off <<= 1) {
    int tmp = (t >= off) ? s[t - off] : 0;
    __syncthreads();
    s[t] += tmp;
    __syncthreads();
  }
  if (t < NBLK) bofs[t] = s[t] - v;
}

__global__ void scanC(int* __restrict__ rowptr, const int* __restrict__ bofs) {
  int i = blockIdx.x * 256 + threadIdx.x;
  if (i < N_NODES) rowptr[i] += bofs[i >> 8];
  if (i == 0) rowptr[N_NODES] = TOT_E;
}

__global__ void fill_kernel(const int* __restrict__ ei, const int* __restrict__ rowptr,
                            int* __restrict__ fill, int* __restrict__ col) {
  int i = blockIdx.x * blockDim.x + threadIdx.x;
  if (i >= TOT_E) return;
  int d = (i < N_EDGES) ? ei[N_EDGES + i] : (i - N_EDGES);
  int s = (i < N_EDGES) ? ei[i] : (i - N_EDGES);
  int pos = rowptr[d] + atomicAdd(&fill[d], 1);
  col[pos] = s;
}

// ---------------- GEMM: H[n,128] = X[n,128] @ W[128,128] ----------------
// tile: 64 rows x 128 cols, K chunked by 64. 256 thr: 16 col-groups x 16 row-groups,
// per-thread 4 rows x 8 cols.
__global__ __launch_bounds__(256) void gemm64(const float* __restrict__ X,
                                              const float* __restrict__ W,
                                              float* __restrict__ H, int nrows) {
  __shared__ float xs[64][68];
  __shared__ float ws[64 * 128];
  int t = threadIdx.x;
  int bm0 = blockIdx.x * 64;
  int cg = t & 15, rg = t >> 4;
  float acc[4][8];
#pragma unroll
  for (int i = 0; i < 4; i++)
#pragma unroll
    for (int j = 0; j < 8; j++) acc[i][j] = 0.f;

  for (int k0 = 0; k0 < 128; k0 += 64) {
    __syncthreads();
#pragma unroll
    for (int q = 0; q < 4; ++q) {          // X tile: 64x64 floats
      int lin4 = q * 256 + t;              // 0..1023 float4s
      int r = lin4 >> 4;
      int kk = (lin4 & 15) << 2;
      float4 v = make_float4(0.f, 0.f, 0.f, 0.f);
      int row = bm0 + r;
      if (row < nrows) v = *(const float4*)(X + (size_t)row * 128 + k0 + kk);
      *(float4*)&xs[r][kk] = v;
    }
#pragma unroll
    for (int q = 0; q < 8; ++q) {          // W chunk: 64x128 floats
      int lin4 = q * 256 + t;              // 0..2047 float4s
      float4 v = *(const float4*)(W + (size_t)k0 * 128 + (size_t)lin4 * 4);
      *(float4*)&ws[lin4 * 4] = v;
    }
    __syncthreads();
    for (int kk = 0; kk < 64; ++kk) {
      float xv[4];
#pragma unroll
      for (int i = 0; i < 4; i++) xv[i] = xs[rg * 4 + i][kk];
      float4 w0 = *(const float4*)&ws[kk * 128 + cg * 8];
      float4 w1 = *(const float4*)&ws[kk * 128 + cg * 8 + 4];
      float wv[8] = {w0.x, w0.y, w0.z, w0.w, w1.x, w1.y, w1.z, w1.w};
#pragma unroll
      for (int i = 0; i < 4; i++)
#pragma unroll
        for (int j = 0; j < 8; j++) acc[i][j] = fmaf(xv[i], wv[j], acc[i][j]);
    }
  }
#pragma unroll
  for (int i = 0; i < 4; i++) {
    int row = bm0 + rg * 4 + i;
    if (row < nrows) {
      float4 o0 = make_float4(acc[i][0], acc[i][1], acc[i][2], acc[i][3]);
      float4 o1 = make_float4(acc[i][4], acc[i][5], acc[i][6], acc[i][7]);
      *(float4*)(H + (size_t)row * 128 + cg * 8) = o0;
      *(float4*)(H + (size_t)row * 128 + cg * 8 + 4) = o1;
    }
  }
}

// ---------------- per-node attention logits: as_[n]=h[n]·a_src, ad_[n]=h[n]·a_dst ----------------
__global__ void alpha_kernel(const float* __restrict__ H, const float* __restrict__ avs,
                             const float* __restrict__ avd, float* __restrict__ outs,
                             float* __restrict__ outd) {
  int gid = blockIdx.x * blockDim.x + threadIdx.x;
  int node = gid >> 6;
  int lane = gid & 63;
  if (node >= N_NODES) return;
  float2 h = ((const float2*)H)[(size_t)node * 64 + lane];
  float2 s2 = ((const float2*)avs)[lane];
  float2 d2 = ((const float2*)avd)[lane];
  float vs = h.x * s2.x + h.y * s2.y;
  float vd = h.x * d2.x + h.y * d2.y;
#pragma unroll
  for (int off = 32; off; off >>= 1) {
    vs += __shfl_xor(vs, off, 64);
    vd += __shfl_xor(vd, off, 64);
  }
  if (lane == 0) { outs[node] = vs; outd[node] = vd; }
}

// ---------------- fused segment-softmax + aggregation + bias + relu ----------------
// one wave per dst node; lane owns dims {2*lane, 2*lane+1}
__global__ void agg_kernel(const float* __restrict__ H, const float* __restrict__ asv,
                           const float* __restrict__ adv, const int* __restrict__ rowptr,
                           const int* __restrict__ col, const float* __restrict__ bias,
                           float* __restrict__ O) {
  int gid = blockIdx.x * blockDim.x + threadIdx.x;
  int node = gid >> 6;
  int lane = gid & 63;
  if (node >= N_NODES) return;
  int r0 = rowptr[node], r1 = rowptr[node + 1];
  float ad = adv[node];
  float2 acc = make_float2(0.f, 0.f);
  float den = 0.f;
  const float2* H2 = (const float2*)H;
  for (int e = r0; e < r1; ++e) {
    int s = col[e];
    float tt = asv[s] + ad;
    tt = (tt > 0.f) ? tt : NEG * tt;
    float ex = __expf(tt);
    den += ex;
    float2 hv = H2[(size_t)s * 64 + lane];
    acc.x = fmaf(ex, hv.x, acc.x);
    acc.y = fmaf(ex, hv.y, acc.y);
  }
  float inv = 1.f / (den + 1e-16f);
  float2 b = ((const float2*)bias)[lane];
  float ox = fmaf(acc.x, inv, b.x);
  float oy = fmaf(acc.y, inv, b.y);
  ((float2*)O)[(size_t)node * 64 + lane] =
      make_float2(ox > 0.f ? ox : 0.f, oy > 0.f ? oy : 0.f);
}

// ---------------- pooling (batch is sorted) ----------------
__global__ void pool_kernel(const float* __restrict__ H, const int* __restrict__ batch,
                            float* __restrict__ psum, float* __restrict__ pcnt,
                            int chunk) {
  int t = threadIdx.x;  // 128
  int start = blockIdx.x * chunk;
  int end = min(N_NODES, start + chunk);
  if (start >= end) return;
  int cur = batch[start];
  float acc = 0.f; int cnt = 0;
  for (int i = start; i < end; ++i) {
    int g = batch[i];
    if (g != cur) {
      atomicAdd(&psum[cur * 128 + t], acc);
      if (t == 0) atomicAdd(&pcnt[cur], (float)cnt);
      acc = 0.f; cnt = 0; cur = g;
    }
    acc += H[(size_t)i * 128 + t];
    cnt++;
  }
  atomicAdd(&psum[cur * 128 + t], acc);
  if (t == 0) atomicAdd(&pcnt[cur], (float)cnt);
}

// ---------------- FFN head ----------------
__global__ void ffn1_kernel(const float* __restrict__ psum, const float* __restrict__ pcnt,
                            const float* __restrict__ Wf1, const float* __restrict__ bf1,
                            float* __restrict__ z1) {
  __shared__ float prow[128];
  int g = blockIdx.x, t = threadIdx.x;  // 512 threads
  if (t < 128) prow[t] = psum[g * 128 + t] / fmaxf(pcnt[g], 1.f);
  __syncthreads();
  float acc = bf1[t];
  for (int k = 0; k < 128; ++k) acc = fmaf(prow[k], Wf1[k * 512 + t], acc);
  z1[g * 512 + t] = fmaxf(acc, 0.f);
}

__global__ void ffn2_kernel(const float* __restrict__ z1, const float* __restrict__ Wf2,
                            const float* __restrict__ bf2, float* __restrict__ z2) {
  __shared__ float zrow[512];
  int g = blockIdx.x, t = threadIdx.x;  // 512 threads
  zrow[t] = z1[g * 512 + t];
  __syncthreads();
  float acc = bf2[t];
  for (int k = 0; k < 512; ++k) acc = fmaf(zrow[k], Wf2[k * 512 + t], acc);
  z2[g * 512 + t] = fmaxf(acc, 0.f);
}

__global__ void ffn3_kernel(const float* __restrict__ z2, const float* __restrict__ Wf3,
                            const float* __restrict__ bf3, float* __restrict__ out) {
  int gid = blockIdx.x * blockDim.x + threadIdx.x;
  if (gid >= NG * NCLS) return;
  int g = gid / NCLS, c = gid % NCLS;
  float acc = bf3[c];
  const float* z = z2 + (size_t)g * 512;
  for (int k = 0; k < 512; ++k) acc = fmaf(z[k], Wf3[k * NCLS + c], acc);
  out[gid] = acc;
}

extern "C" void kernel_launch(void* const* d_in, const int* in_sizes, int n_in,
                              void* d_out, int out_size, void* d_ws, size_t ws_size,
                              hipStream_t stream) {
  const float* x   = (const float*)d_in[0];
  const int*   ei  = (const int*)d_in[1];
  const int*   bat = (const int*)d_in[2];
  const float* W[3]  = {(const float*)d_in[3], (const float*)d_in[7],  (const float*)d_in[11]};
  const float* As[3] = {(const float*)d_in[4], (const float*)d_in[8],  (const float*)d_in[12]};
  const float* Ad[3] = {(const float*)d_in[5], (const float*)d_in[9],  (const float*)d_in[13]};
  const float* B[3]  = {(const float*)d_in[6], (const float*)d_in[10], (const float*)d_in[14]};
  const float* Wf1 = (const float*)d_in[15]; const float* bf1 = (const float*)d_in[16];
  const float* Wf2 = (const float*)d_in[17]; const float* bf2 = (const float*)d_in[18];
  const float* Wf3 = (const float*)d_in[19]; const float* bf3 = (const float*)d_in[20];
  float* out = (float*)d_out;

  // workspace carve-up (256B aligned)
  size_t off = 0;
  auto carve = [&](size_t bytes) {
    void* p = (char*)d_ws + off;
    off += (bytes + 255) & ~(size_t)255;
    return p;
  };
  float* hA     = (float*)carve((size_t)N_NODES * 128 * 4);
  float* hB     = (float*)carve((size_t)N_NODES * 128 * 4);
  float* as_    = (float*)carve((size_t)N_NODES * 4);
  float* ad_    = (float*)carve((size_t)N_NODES * 4);
  int*   deg    = (int*)carve((size_t)N_NODES * 4);
  int*   fil    = (int*)carve((size_t)N_NODES * 4);
  int*   rowptr = (int*)carve((size_t)(N_NODES + 1) * 4);
  int*   col    = (int*)carve((size_t)TOT_E * 4);
  int*   bsum   = (int*)carve(256 * 4);
  int*   bofs   = (int*)carve(256 * 4);
  float* psum   = (float*)carve(128 * 128 * 4);
  float* pcnt   = (float*)carve(128 * 4);
  float* z1     = (float*)carve(128 * 512 * 4);
  float* z2     = (float*)carve(128 * 512 * 4);

  hipMemsetAsync(deg, 0, (size_t)N_NODES * 4, stream);
  hipMemsetAsync(fil, 0, (size_t)N_NODES * 4, stream);
  hipMemsetAsync(psum, 0, 128 * 128 * 4, stream);
  hipMemsetAsync(pcnt, 0, 128 * 4, stream);

  // CSR build
  int eb = (TOT_E + 255) / 256;
  count_kernel<<<eb, 256, 0, stream>>>(ei, deg);
  scanA<<<NBLK, 256, 0, stream>>>(deg, rowptr, bsum);
  scanB<<<1, 256, 0, stream>>>(bsum, bofs);
  scanC<<<NBLK, 256, 0, stream>>>(rowptr, bofs);
  fill_kernel<<<eb, 256, 0, stream>>>(ei, rowptr, fil, col);

  // 3 GAT layers: gemm -> alpha -> fused softmax-agg (+bias+relu)
  int gemm_grid = (N_NODES + 63) / 64;
  int node_waves_grid = (N_NODES * 64 + 255) / 256;  // one wave per node
  const float* in_ptr = x;
  for (int l = 0; l < 3; ++l) {
    gemm64<<<gemm_grid, 256, 0, stream>>>(in_ptr, W[l], hA, N_NODES);
    alpha_kernel<<<node_waves_grid, 256, 0, stream>>>(hA, As[l], Ad[l], as_, ad_);
    agg_kernel<<<node_waves_grid, 256, 0, stream>>>(hA, as_, ad_, rowptr, col, B[l], hB);
    in_ptr = hB;
  }

  // mean-pool + FFN
  pool_kernel<<<(N_NODES + 511) / 512, 128, 0, stream>>>(hB, bat, psum, pcnt, 512);
  ffn1_kernel<<<NG, 512, 0, stream>>>(psum, pcnt, Wf1, bf1, z1);
  ffn2_kernel<<<NG, 512, 0, stream>>>(z1, Wf2, bf2, z2);
  ffn3_kernel<<<(NG * NCLS + 63) / 64, 64, 0, stream>>>(z2, Wf3, bf3, out);
}

// Round 2
// 422.349 us; speedup vs baseline: 1.4889x; 1.4889x over previous
//
#include <hip/hip_runtime.h>

#define N_NODES 50000
#define N_EDGES 640000
#define TOT_E (N_EDGES + N_NODES)
#define NBLK 196            // ceil(N_NODES/256)
#define NG 128
#define DFFN 512
#define NCLS 10
#define NEG 0.2f
#define PCHUNK 50

// ---------------- CSR build ----------------
__global__ void count_kernel(const int* __restrict__ ei, int* __restrict__ deg) {
  int i = blockIdx.x * blockDim.x + threadIdx.x;
  if (i >= TOT_E) return;
  int d = (i < N_EDGES) ? ei[N_EDGES + i] : (i - N_EDGES);
  atomicAdd(&deg[d], 1);
}

__global__ void scanA(const int* __restrict__ deg, int* __restrict__ rowptr,
                      int* __restrict__ bsum) {
  __shared__ int s[256];
  int t = threadIdx.x;
  int i = blockIdx.x * 256 + t;
  int v = (i < N_NODES) ? deg[i] : 0;
  s[t] = v; __syncthreads();
  for (int off = 1; off < 256; off <<= 1) {
    int tmp = (t >= off) ? s[t - off] : 0;
    __syncthreads();
    s[t] += tmp;
    __syncthreads();
  }
  if (i < N_NODES) rowptr[i] = s[t] - v;   // exclusive, block-local
  if (t == 255) bsum[blockIdx.x] = s[255];
}

__global__ void scanB(const int* __restrict__ bsum, int* __restrict__ bofs) {
  __shared__ int s[256];
  int t = threadIdx.x;
  int v = (t < NBLK) ? bsum[t] : 0;
  s[t] = v; __syncthreads();
  for (int off = 1; off < 256; off <<= 1) {
    int tmp = (t >= off) ? s[t - off] : 0;
    __syncthreads();
    s[t] += tmp;
    __syncthreads();
  }
  if (t < NBLK) bofs[t] = s[t] - v;
}

__global__ void scanC(int* __restrict__ rowptr, const int* __restrict__ bofs) {
  int i = blockIdx.x * 256 + threadIdx.x;
  if (i < N_NODES) rowptr[i] += bofs[i >> 8];
  if (i == 0) rowptr[N_NODES] = TOT_E;
}

__global__ void fill_kernel(const int* __restrict__ ei, const int* __restrict__ rowptr,
                            int* __restrict__ fill, int* __restrict__ col) {
  int i = blockIdx.x * blockDim.x + threadIdx.x;
  if (i >= TOT_E) return;
  int d = (i < N_EDGES) ? ei[N_EDGES + i] : (i - N_EDGES);
  int s = (i < N_EDGES) ? ei[i] : (i - N_EDGES);
  int pos = rowptr[d] + atomicAdd(&fill[d], 1);
  col[pos] = s;
}

// ---------------- GEMM: H[n,128] = X[n,128] @ W[128,128] ----------------
__global__ __launch_bounds__(256) void gemm64(const float* __restrict__ X,
                                              const float* __restrict__ W,
                                              float* __restrict__ H, int nrows) {
  __shared__ float xs[64][68];
  __shared__ float ws[64 * 128];
  int t = threadIdx.x;
  int bm0 = blockIdx.x * 64;
  int cg = t & 15, rg = t >> 4;
  float acc[4][8];
#pragma unroll
  for (int i = 0; i < 4; i++)
#pragma unroll
    for (int j = 0; j < 8; j++) acc[i][j] = 0.f;

  for (int k0 = 0; k0 < 128; k0 += 64) {
    __syncthreads();
#pragma unroll
    for (int q = 0; q < 4; ++q) {          // X tile: 64x64 floats
      int lin4 = q * 256 + t;              // 0..1023 float4s
      int r = lin4 >> 4;
      int kk = (lin4 & 15) << 2;
      float4 v = make_float4(0.f, 0.f, 0.f, 0.f);
      int row = bm0 + r;
      if (row < nrows) v = *(const float4*)(X + (size_t)row * 128 + k0 + kk);
      *(float4*)&xs[r][kk] = v;
    }
#pragma unroll
    for (int q = 0; q < 8; ++q) {          // W chunk: 64x128 floats
      int lin4 = q * 256 + t;              // 0..2047 float4s
      float4 v = *(const float4*)(W + (size_t)k0 * 128 + (size_t)lin4 * 4);
      *(float4*)&ws[lin4 * 4] = v;
    }
    __syncthreads();
    for (int kk = 0; kk < 64; ++kk) {
      float xv[4];
#pragma unroll
      for (int i = 0; i < 4; i++) xv[i] = xs[rg * 4 + i][kk];
      float4 w0 = *(const float4*)&ws[kk * 128 + cg * 8];
      float4 w1 = *(const float4*)&ws[kk * 128 + cg * 8 + 4];
      float wv[8] = {w0.x, w0.y, w0.z, w0.w, w1.x, w1.y, w1.z, w1.w};
#pragma unroll
      for (int i = 0; i < 4; i++)
#pragma unroll
        for (int j = 0; j < 8; j++) acc[i][j] = fmaf(xv[i], wv[j], acc[i][j]);
    }
  }
#pragma unroll
  for (int i = 0; i < 4; i++) {
    int row = bm0 + rg * 4 + i;
    if (row < nrows) {
      float4 o0 = make_float4(acc[i][0], acc[i][1], acc[i][2], acc[i][3]);
      float4 o1 = make_float4(acc[i][4], acc[i][5], acc[i][6], acc[i][7]);
      *(float4*)(H + (size_t)row * 128 + cg * 8) = o0;
      *(float4*)(H + (size_t)row * 128 + cg * 8 + 4) = o1;
    }
  }
}

// ---------------- per-node attention logits ----------------
__global__ void alpha_kernel(const float* __restrict__ H, const float* __restrict__ avs,
                             const float* __restrict__ avd, float* __restrict__ outs,
                             float* __restrict__ outd) {
  int gid = blockIdx.x * blockDim.x + threadIdx.x;
  int node = gid >> 6;
  int lane = threadIdx.x & 63;
  if (node >= N_NODES) return;
  float2 h = ((const float2*)H)[(size_t)node * 64 + lane];
  float2 s2 = ((const float2*)avs)[lane];
  float2 d2 = ((const float2*)avd)[lane];
  float vs = h.x * s2.x + h.y * s2.y;
  float vd = h.x * d2.x + h.y * d2.y;
#pragma unroll
  for (int off = 32; off; off >>= 1) {
    vs += __shfl_xor(vs, off, 64);
    vd += __shfl_xor(vd, off, 64);
  }
  if (lane == 0) { outs[node] = vs; outd[node] = vd; }
}

// ---------------- fused segment-softmax + aggregation + bias + relu ----------------
// one wave per dst node; half-wave owns an edge, li = lane&31 owns float4 of dims.
// Lane-parallel precompute of all edge weights breaks the serial latency chain.
__global__ __launch_bounds__(256) void agg_kernel(
    const float* __restrict__ H, const float* __restrict__ asv,
    const float* __restrict__ adv, const int* __restrict__ rowptr,
    const int* __restrict__ col, const float* __restrict__ bias,
    float* __restrict__ O) {
  int gid = blockIdx.x * blockDim.x + threadIdx.x;
  int node = gid >> 6;
  if (node >= N_NODES) return;
  int lane = threadIdx.x & 63;
  int half = lane >> 5;
  int li = lane & 31;
  int r0 = rowptr[node], r1 = rowptr[node + 1];
  float ad = adv[node];
  float4 acc = make_float4(0.f, 0.f, 0.f, 0.f);
  float den = 0.f;
  const float4* H4 = (const float4*)H;

  for (int base = r0; base < r1; base += 64) {
    int cnt = min(64, r1 - base);
    int s_l = 0; float ex_l = 0.f;
    if (lane < cnt) {
      s_l = col[base + lane];
      float tt = asv[s_l] + ad;
      tt = (tt > 0.f) ? tt : NEG * tt;
      ex_l = __expf(tt);
    }
    // denom: wave-sum of ex_l
    float d = ex_l;
#pragma unroll
    for (int off = 32; off; off >>= 1) d += __shfl_xor(d, off, 64);
    den += d;

    // gather: 2 edges per wave step, unrolled x2 -> 4 loads in flight
    int j = 0;
    for (; j + 4 <= cnt; j += 4) {
      int idx0 = j + half, idx1 = j + 2 + half;
      int s0 = __shfl(s_l, idx0, 64);
      float e0 = __shfl(ex_l, idx0, 64);
      int s1 = __shfl(s_l, idx1, 64);
      float e1 = __shfl(ex_l, idx1, 64);
      float4 h0 = H4[(size_t)s0 * 32 + li];
      float4 h1 = H4[(size_t)s1 * 32 + li];
      acc.x = fmaf(e0, h0.x, acc.x); acc.y = fmaf(e0, h0.y, acc.y);
      acc.z = fmaf(e0, h0.z, acc.z); acc.w = fmaf(e0, h0.w, acc.w);
      acc.x = fmaf(e1, h1.x, acc.x); acc.y = fmaf(e1, h1.y, acc.y);
      acc.z = fmaf(e1, h1.z, acc.z); acc.w = fmaf(e1, h1.w, acc.w);
    }
    for (; j < cnt; j += 2) {
      int idx = j + half;
      int sj = __shfl(s_l, idx, 64);
      float ej = __shfl(ex_l, idx, 64);
      if (idx < cnt) {
        float4 hv = H4[(size_t)sj * 32 + li];
        acc.x = fmaf(ej, hv.x, acc.x); acc.y = fmaf(ej, hv.y, acc.y);
        acc.z = fmaf(ej, hv.z, acc.z); acc.w = fmaf(ej, hv.w, acc.w);
      }
    }
  }
  // merge the two half-wave partial sums (same dims, disjoint edge subsets)
  acc.x += __shfl_xor(acc.x, 32, 64);
  acc.y += __shfl_xor(acc.y, 32, 64);
  acc.z += __shfl_xor(acc.z, 32, 64);
  acc.w += __shfl_xor(acc.w, 32, 64);

  if (half == 0) {
    float inv = 1.f / (den + 1e-16f);
    float4 b = ((const float4*)bias)[li];
    float4 o;
    o.x = fmaxf(fmaf(acc.x, inv, b.x), 0.f);
    o.y = fmaxf(fmaf(acc.y, inv, b.y), 0.f);
    o.z = fmaxf(fmaf(acc.z, inv, b.z), 0.f);
    o.w = fmaxf(fmaf(acc.w, inv, b.w), 0.f);
    ((float4*)O)[(size_t)node * 32 + li] = o;
  }
}

// ---------------- pooling (batch is sorted) ----------------
__global__ void pool_kernel(const float* __restrict__ H, const int* __restrict__ batch,
                            float* __restrict__ psum, float* __restrict__ pcnt) {
  int t = threadIdx.x;  // 128
  int start = blockIdx.x * PCHUNK;
  int end = min(N_NODES, start + PCHUNK);
  if (start >= end) return;
  int cur = batch[start];
  float acc = 0.f; int cnt = 0;
  for (int i = start; i < end; ++i) {
    int g = batch[i];
    if (g != cur) {
      atomicAdd(&psum[cur * 128 + t], acc);
      if (t == 0) atomicAdd(&pcnt[cur], (float)cnt);
      acc = 0.f; cnt = 0; cur = g;
    }
    acc += H[(size_t)i * 128 + t];
    cnt++;
  }
  atomicAdd(&psum[cur * 128 + t], acc);
  if (t == 0) atomicAdd(&pcnt[cur], (float)cnt);
}

// ---------------- FFN head ----------------
__global__ void ffn1_kernel(const float* __restrict__ psum, const float* __restrict__ pcnt,
                            const float* __restrict__ Wf1, const float* __restrict__ bf1,
                            float* __restrict__ z1) {
  __shared__ float prow[128];
  int g = blockIdx.x, t = threadIdx.x;  // 512 threads
  if (t < 128) prow[t] = psum[g * 128 + t] / fmaxf(pcnt[g], 1.f);
  __syncthreads();
  float acc = bf1[t];
  for (int k = 0; k < 128; ++k) acc = fmaf(prow[k], Wf1[k * 512 + t], acc);
  z1[g * 512 + t] = fmaxf(acc, 0.f);
}

__global__ void ffn2_kernel(const float* __restrict__ z1, const float* __restrict__ Wf2,
                            const float* __restrict__ bf2, float* __restrict__ z2) {
  __shared__ float zrow[512];
  int g = blockIdx.x, t = threadIdx.x;  // 512 threads
  zrow[t] = z1[g * 512 + t];
  __syncthreads();
  float acc = bf2[t];
  for (int k = 0; k < 512; ++k) acc = fmaf(zrow[k], Wf2[k * 512 + t], acc);
  z2[g * 512 + t] = fmaxf(acc, 0.f);
}

__global__ void ffn3_kernel(const float* __restrict__ z2, const float* __restrict__ Wf3,
                            const float* __restrict__ bf3, float* __restrict__ out) {
  int gid = blockIdx.x * blockDim.x + threadIdx.x;
  if (gid >= NG * NCLS) return;
  int g = gid / NCLS, c = gid % NCLS;
  float acc = bf3[c];
  const float* z = z2 + (size_t)g * 512;
  for (int k = 0; k < 512; ++k) acc = fmaf(z[k], Wf3[k * NCLS + c], acc);
  out[gid] = acc;
}

extern "C" void kernel_launch(void* const* d_in, const int* in_sizes, int n_in,
                              void* d_out, int out_size, void* d_ws, size_t ws_size,
                              hipStream_t stream) {
  const float* x   = (const float*)d_in[0];
  const int*   ei  = (const int*)d_in[1];
  const int*   bat = (const int*)d_in[2];
  const float* W[3]  = {(const float*)d_in[3], (const float*)d_in[7],  (const float*)d_in[11]};
  const float* As[3] = {(const float*)d_in[4], (const float*)d_in[8],  (const float*)d_in[12]};
  const float* Ad[3] = {(const float*)d_in[5], (const float*)d_in[9],  (const float*)d_in[13]};
  const float* B[3]  = {(const float*)d_in[6], (const float*)d_in[10], (const float*)d_in[14]};
  const float* Wf1 = (const float*)d_in[15]; const float* bf1 = (const float*)d_in[16];
  const float* Wf2 = (const float*)d_in[17]; const float* bf2 = (const float*)d_in[18];
  const float* Wf3 = (const float*)d_in[19]; const float* bf3 = (const float*)d_in[20];
  float* out = (float*)d_out;

  size_t off = 0;
  auto carve = [&](size_t bytes) {
    void* p = (char*)d_ws + off;
    off += (bytes + 255) & ~(size_t)255;
    return p;
  };
  float* hA     = (float*)carve((size_t)N_NODES * 128 * 4);
  float* hB     = (float*)carve((size_t)N_NODES * 128 * 4);
  float* as_    = (float*)carve((size_t)N_NODES * 4);
  float* ad_    = (float*)carve((size_t)N_NODES * 4);
  int*   deg    = (int*)carve((size_t)N_NODES * 4);
  int*   fil    = (int*)carve((size_t)N_NODES * 4);
  int*   rowptr = (int*)carve((size_t)(N_NODES + 1) * 4);
  int*   col    = (int*)carve((size_t)TOT_E * 4);
  int*   bsum   = (int*)carve(256 * 4);
  int*   bofs   = (int*)carve(256 * 4);
  float* psum   = (float*)carve(128 * 128 * 4);
  float* pcnt   = (float*)carve(128 * 4);
  float* z1     = (float*)carve(128 * 512 * 4);
  float* z2     = (float*)carve(128 * 512 * 4);

  hipMemsetAsync(deg, 0, (size_t)N_NODES * 4, stream);
  hipMemsetAsync(fil, 0, (size_t)N_NODES * 4, stream);
  hipMemsetAsync(psum, 0, 128 * 128 * 4, stream);
  hipMemsetAsync(pcnt, 0, 128 * 4, stream);

  // CSR build
  int eb = (TOT_E + 255) / 256;
  count_kernel<<<eb, 256, 0, stream>>>(ei, deg);
  scanA<<<NBLK, 256, 0, stream>>>(deg, rowptr, bsum);
  scanB<<<1, 256, 0, stream>>>(bsum, bofs);
  scanC<<<NBLK, 256, 0, stream>>>(rowptr, bofs);
  fill_kernel<<<eb, 256, 0, stream>>>(ei, rowptr, fil, col);

  // 3 GAT layers
  int gemm_grid = (N_NODES + 63) / 64;
  int node_waves_grid = (N_NODES * 64 + 255) / 256;
  const float* in_ptr = x;
  for (int l = 0; l < 3; ++l) {
    gemm64<<<gemm_grid, 256, 0, stream>>>(in_ptr, W[l], hA, N_NODES);
    alpha_kernel<<<node_waves_grid, 256, 0, stream>>>(hA, As[l], Ad[l], as_, ad_);
    agg_kernel<<<node_waves_grid, 256, 0, stream>>>(hA, as_, ad_, rowptr, col, B[l], hB);
    in_ptr = hB;
  }

  // mean-pool + FFN
  pool_kernel<<<(N_NODES + PCHUNK - 1) / PCHUNK, 128, 0, stream>>>(hB, bat, psum, pcnt);
  ffn1_kernel<<<NG, 512, 0, stream>>>(psum, pcnt, Wf1, bf1, z1);
  ffn2_kernel<<<NG, 512, 0, stream>>>(z1, Wf2, bf2, z2);
  ffn3_kernel<<<(NG * NCLS + 63) / 64, 64, 0, stream>>>(z2, Wf3, bf3, out);
}

// Round 3
// 351.672 us; speedup vs baseline: 1.7881x; 1.2010x over previous
//
#include <hip/hip_runtime.h>

#define N_NODES 50000
#define N_EDGES 640000
#define TOT_E (N_EDGES + N_NODES)
#define NBLK 196            // ceil(N_NODES/256)
#define NG 128
#define NCLS 10
#define NEG 0.2f
#define PCHUNK 50

typedef unsigned int u32;
typedef unsigned short u16;

__device__ inline u32 bf16rne(float f) {
  u32 u = __float_as_uint(f);
  return (u + 0x7FFFu + ((u >> 16) & 1u)) >> 16;
}

// ---------------- CSR build ----------------
__global__ void count_kernel(const int* __restrict__ ei, int* __restrict__ deg) {
  int i = blockIdx.x * blockDim.x + threadIdx.x;
  if (i >= TOT_E) return;
  int d = (i < N_EDGES) ? ei[N_EDGES + i] : (i - N_EDGES);
  atomicAdd(&deg[d], 1);
}

__global__ void scanA(const int* __restrict__ deg, int* __restrict__ rowptr,
                      int* __restrict__ bsum) {
  __shared__ int s[256];
  int t = threadIdx.x;
  int i = blockIdx.x * 256 + t;
  int v = (i < N_NODES) ? deg[i] : 0;
  s[t] = v; __syncthreads();
  for (int off = 1; off < 256; off <<= 1) {
    int tmp = (t >= off) ? s[t - off] : 0;
    __syncthreads();
    s[t] += tmp;
    __syncthreads();
  }
  if (i < N_NODES) rowptr[i] = s[t] - v;
  if (t == 255) bsum[blockIdx.x] = s[255];
}

__global__ void scanB(const int* __restrict__ bsum, int* __restrict__ bofs) {
  __shared__ int s[256];
  int t = threadIdx.x;
  int v = (t < NBLK) ? bsum[t] : 0;
  s[t] = v; __syncthreads();
  for (int off = 1; off < 256; off <<= 1) {
    int tmp = (t >= off) ? s[t - off] : 0;
    __syncthreads();
    s[t] += tmp;
    __syncthreads();
  }
  if (t < NBLK) bofs[t] = s[t] - v;
}

__global__ void scanC(int* __restrict__ rowptr, const int* __restrict__ bofs) {
  int i = blockIdx.x * 256 + threadIdx.x;
  if (i < N_NODES) rowptr[i] += bofs[i >> 8];
  if (i == 0) rowptr[N_NODES] = TOT_E;
}

__global__ void fill_kernel(const int* __restrict__ ei, const int* __restrict__ rowptr,
                            int* __restrict__ fill, int* __restrict__ col) {
  int i = blockIdx.x * blockDim.x + threadIdx.x;
  if (i >= TOT_E) return;
  int d = (i < N_EDGES) ? ei[N_EDGES + i] : (i - N_EDGES);
  int s = (i < N_EDGES) ? ei[i] : (i - N_EDGES);
  int pos = rowptr[d] + atomicAdd(&fill[d], 1);
  col[pos] = s;
}

// ---------------- GEMM + fused alpha + bf16 pack ----------------
// H = X @ W; writes Hb (bf16), as_[n] = h·a_src, ad_[n] = h·a_dst
__global__ __launch_bounds__(256) void gemm64(const float* __restrict__ X,
                                              const float* __restrict__ W,
                                              const float* __restrict__ avs,
                                              const float* __restrict__ avd,
                                              u16* __restrict__ Hb,
                                              float* __restrict__ as_out,
                                              float* __restrict__ ad_out,
                                              int nrows) {
  __shared__ float xs[64][68];
  __shared__ float ws[64 * 128];
  int t = threadIdx.x;
  int bm0 = blockIdx.x * 64;
  int cg = t & 15, rg = t >> 4;
  float acc[4][8];
#pragma unroll
  for (int i = 0; i < 4; i++)
#pragma unroll
    for (int j = 0; j < 8; j++) acc[i][j] = 0.f;

  for (int k0 = 0; k0 < 128; k0 += 64) {
    __syncthreads();
#pragma unroll
    for (int q = 0; q < 4; ++q) {
      int lin4 = q * 256 + t;
      int r = lin4 >> 4;
      int kk = (lin4 & 15) << 2;
      float4 v = make_float4(0.f, 0.f, 0.f, 0.f);
      int row = bm0 + r;
      if (row < nrows) v = *(const float4*)(X + (size_t)row * 128 + k0 + kk);
      *(float4*)&xs[r][kk] = v;
    }
#pragma unroll
    for (int q = 0; q < 8; ++q) {
      int lin4 = q * 256 + t;
      float4 v = *(const float4*)(W + (size_t)k0 * 128 + (size_t)lin4 * 4);
      *(float4*)&ws[lin4 * 4] = v;
    }
    __syncthreads();
    for (int kk = 0; kk < 64; ++kk) {
      float xv[4];
#pragma unroll
      for (int i = 0; i < 4; i++) xv[i] = xs[rg * 4 + i][kk];
      float4 w0 = *(const float4*)&ws[kk * 128 + cg * 8];
      float4 w1 = *(const float4*)&ws[kk * 128 + cg * 8 + 4];
      float wv[8] = {w0.x, w0.y, w0.z, w0.w, w1.x, w1.y, w1.z, w1.w};
#pragma unroll
      for (int i = 0; i < 4; i++)
#pragma unroll
        for (int j = 0; j < 8; j++) acc[i][j] = fmaf(xv[i], wv[j], acc[i][j]);
    }
  }

  // epilogue: fused alpha + bf16 store
  float as_v[8], ad_v[8];
#pragma unroll
  for (int j = 0; j < 8; j++) {
    as_v[j] = avs[cg * 8 + j];
    ad_v[j] = avd[cg * 8 + j];
  }
#pragma unroll
  for (int i = 0; i < 4; i++) {
    int row = bm0 + rg * 4 + i;
    if (row < nrows) {   // uniform within the 16-lane cg-group
      float ps = 0.f, pd = 0.f;
#pragma unroll
      for (int j = 0; j < 8; j++) {
        ps = fmaf(acc[i][j], as_v[j], ps);
        pd = fmaf(acc[i][j], ad_v[j], pd);
      }
#pragma unroll
      for (int off = 8; off; off >>= 1) {
        ps += __shfl_xor(ps, off, 64);
        pd += __shfl_xor(pd, off, 64);
      }
      if (cg == 0) { as_out[row] = ps; ad_out[row] = pd; }
      u32 p0 = bf16rne(acc[i][0]) | (bf16rne(acc[i][1]) << 16);
      u32 p1 = bf16rne(acc[i][2]) | (bf16rne(acc[i][3]) << 16);
      u32 p2 = bf16rne(acc[i][4]) | (bf16rne(acc[i][5]) << 16);
      u32 p3 = bf16rne(acc[i][6]) | (bf16rne(acc[i][7]) << 16);
      uint4 st = make_uint4(p0, p1, p2, p3);
      *(uint4*)(Hb + (size_t)row * 128 + cg * 8) = st;
    }
  }
}

// ---------------- fused segment-softmax + aggregation + bias + relu ----------------
// one wave per dst node; quarter-wave (16 lanes x 16B) per edge row (bf16).
__global__ __launch_bounds__(256) void agg_kernel(
    const u16* __restrict__ Hb, const float* __restrict__ asv,
    const float* __restrict__ adv, const int* __restrict__ rowptr,
    const int* __restrict__ col, const float* __restrict__ bias,
    float* __restrict__ O) {
  int gid = blockIdx.x * blockDim.x + threadIdx.x;
  int node = gid >> 6;
  if (node >= N_NODES) return;
  int lane = threadIdx.x & 63;
  int q = lane >> 4;
  int li = lane & 15;
  int r0 = rowptr[node], r1 = rowptr[node + 1];
  float ad = adv[node];
  float acc[8];
#pragma unroll
  for (int k = 0; k < 8; k++) acc[k] = 0.f;
  float den = 0.f;

  for (int base = r0; base < r1; base += 64) {
    int cnt = min(64, r1 - base);
    int s_l = 0; float ex_l = 0.f;
    if (lane < cnt) {
      s_l = col[base + lane];
      float tt = asv[s_l] + ad;
      tt = (tt > 0.f) ? tt : NEG * tt;
      ex_l = __expf(tt);
    }
    float d = ex_l;
#pragma unroll
    for (int off = 32; off; off >>= 1) d += __shfl_xor(d, off, 64);
    den += d;

    int j = 0;
    for (; j + 8 <= cnt; j += 8) {
      int i0 = j + q, i1 = j + 4 + q;
      int s0 = __shfl(s_l, i0, 64); float e0 = __shfl(ex_l, i0, 64);
      int s1 = __shfl(s_l, i1, 64); float e1 = __shfl(ex_l, i1, 64);
      uint4 h0 = *(const uint4*)(Hb + (size_t)s0 * 128 + li * 8);
      uint4 h1 = *(const uint4*)(Hb + (size_t)s1 * 128 + li * 8);
      u32 w0[4] = {h0.x, h0.y, h0.z, h0.w};
      u32 w1[4] = {h1.x, h1.y, h1.z, h1.w};
#pragma unroll
      for (int k = 0; k < 4; k++) {
        acc[2*k]   = fmaf(e0, __uint_as_float(w0[k] << 16), acc[2*k]);
        acc[2*k+1] = fmaf(e0, __uint_as_float(w0[k] & 0xFFFF0000u), acc[2*k+1]);
      }
#pragma unroll
      for (int k = 0; k < 4; k++) {
        acc[2*k]   = fmaf(e1, __uint_as_float(w1[k] << 16), acc[2*k]);
        acc[2*k+1] = fmaf(e1, __uint_as_float(w1[k] & 0xFFFF0000u), acc[2*k+1]);
      }
    }
    for (; j < cnt; j += 4) {
      int i0 = j + q;
      int s0 = __shfl(s_l, i0, 64); float e0 = __shfl(ex_l, i0, 64);
      if (i0 < cnt) {
        uint4 h0 = *(const uint4*)(Hb + (size_t)s0 * 128 + li * 8);
        u32 w0[4] = {h0.x, h0.y, h0.z, h0.w};
#pragma unroll
        for (int k = 0; k < 4; k++) {
          acc[2*k]   = fmaf(e0, __uint_as_float(w0[k] << 16), acc[2*k]);
          acc[2*k+1] = fmaf(e0, __uint_as_float(w0[k] & 0xFFFF0000u), acc[2*k+1]);
        }
      }
    }
  }
  // merge the 4 quarter partial sums (same dims, disjoint edges)
#pragma unroll
  for (int k = 0; k < 8; k++) {
    acc[k] += __shfl_xor(acc[k], 16, 64);
    acc[k] += __shfl_xor(acc[k], 32, 64);
  }

  if (q == 0) {
    float inv = 1.f / (den + 1e-16f);
    float4 b0 = *(const float4*)(bias + li * 8);
    float4 b1 = *(const float4*)(bias + li * 8 + 4);
    float4 o0, o1;
    o0.x = fmaxf(fmaf(acc[0], inv, b0.x), 0.f);
    o0.y = fmaxf(fmaf(acc[1], inv, b0.y), 0.f);
    o0.z = fmaxf(fmaf(acc[2], inv, b0.z), 0.f);
    o0.w = fmaxf(fmaf(acc[3], inv, b0.w), 0.f);
    o1.x = fmaxf(fmaf(acc[4], inv, b1.x), 0.f);
    o1.y = fmaxf(fmaf(acc[5], inv, b1.y), 0.f);
    o1.z = fmaxf(fmaf(acc[6], inv, b1.z), 0.f);
    o1.w = fmaxf(fmaf(acc[7], inv, b1.w), 0.f);
    *(float4*)(O + (size_t)node * 128 + li * 8) = o0;
    *(float4*)(O + (size_t)node * 128 + li * 8 + 4) = o1;
  }
}

// ---------------- pooling (batch is sorted) ----------------
__global__ void pool_kernel(const float* __restrict__ H, const int* __restrict__ batch,
                            float* __restrict__ psum, float* __restrict__ pcnt) {
  int t = threadIdx.x;  // 128
  int start = blockIdx.x * PCHUNK;
  int end = min(N_NODES, start + PCHUNK);
  if (start >= end) return;
  int cur = batch[start];
  float acc = 0.f; int cnt = 0;
  for (int i = start; i < end; ++i) {
    int g = batch[i];
    if (g != cur) {
      atomicAdd(&psum[cur * 128 + t], acc);
      if (t == 0) atomicAdd(&pcnt[cur], (float)cnt);
      acc = 0.f; cnt = 0; cur = g;
    }
    acc += H[(size_t)i * 128 + t];
    cnt++;
  }
  atomicAdd(&psum[cur * 128 + t], acc);
  if (t == 0) atomicAdd(&pcnt[cur], (float)cnt);
}

// ---------------- FFN head ----------------
__global__ void ffn1_kernel(const float* __restrict__ psum, const float* __restrict__ pcnt,
                            const float* __restrict__ Wf1, const float* __restrict__ bf1,
                            float* __restrict__ z1) {
  __shared__ float prow[128];
  int g = blockIdx.x, t = threadIdx.x;  // 512
  if (t < 128) prow[t] = psum[g * 128 + t] / fmaxf(pcnt[g], 1.f);
  __syncthreads();
  float acc = bf1[t];
  for (int k = 0; k < 128; ++k) acc = fmaf(prow[k], Wf1[k * 512 + t], acc);
  z1[g * 512 + t] = fmaxf(acc, 0.f);
}

__global__ void ffn2_kernel(const float* __restrict__ z1, const float* __restrict__ Wf2,
                            const float* __restrict__ bf2, float* __restrict__ z2) {
  __shared__ float zrow[512];
  int g = blockIdx.x, t = threadIdx.x;  // 512
  zrow[t] = z1[g * 512 + t];
  __syncthreads();
  float acc = bf2[t];
  for (int k = 0; k < 512; ++k) acc = fmaf(zrow[k], Wf2[k * 512 + t], acc);
  z2[g * 512 + t] = fmaxf(acc, 0.f);
}

__global__ void ffn3_kernel(const float* __restrict__ z2, const float* __restrict__ Wf3,
                            const float* __restrict__ bf3, float* __restrict__ out) {
  int gid = blockIdx.x * blockDim.x + threadIdx.x;
  if (gid >= NG * NCLS) return;
  int g = gid / NCLS, c = gid % NCLS;
  float acc = bf3[c];
  const float* z = z2 + (size_t)g * 512;
  for (int k = 0; k < 512; ++k) acc = fmaf(z[k], Wf3[k * NCLS + c], acc);
  out[gid] = acc;
}

extern "C" void kernel_launch(void* const* d_in, const int* in_sizes, int n_in,
                              void* d_out, int out_size, void* d_ws, size_t ws_size,
                              hipStream_t stream) {
  const float* x   = (const float*)d_in[0];
  const int*   ei  = (const int*)d_in[1];
  const int*   bat = (const int*)d_in[2];
  const float* W[3]  = {(const float*)d_in[3], (const float*)d_in[7],  (const float*)d_in[11]};
  const float* As[3] = {(const float*)d_in[4], (const float*)d_in[8],  (const float*)d_in[12]};
  const float* Ad[3] = {(const float*)d_in[5], (const float*)d_in[9],  (const float*)d_in[13]};
  const float* B[3]  = {(const float*)d_in[6], (const float*)d_in[10], (const float*)d_in[14]};
  const float* Wf1 = (const float*)d_in[15]; const float* bf1 = (const float*)d_in[16];
  const float* Wf2 = (const float*)d_in[17]; const float* bf2 = (const float*)d_in[18];
  const float* Wf3 = (const float*)d_in[19]; const float* bf3 = (const float*)d_in[20];
  float* out = (float*)d_out;

  size_t off = 0;
  auto carve = [&](size_t bytes) {
    void* p = (char*)d_ws + off;
    off += (bytes + 255) & ~(size_t)255;
    return p;
  };
  u16*   Hb     = (u16*)carve((size_t)N_NODES * 128 * 2);
  float* hB     = (float*)carve((size_t)N_NODES * 128 * 4);
  float* as_    = (float*)carve((size_t)N_NODES * 4);
  float* ad_    = (float*)carve((size_t)N_NODES * 4);
  int*   deg    = (int*)carve((size_t)N_NODES * 4);
  int*   fil    = (int*)carve((size_t)N_NODES * 4);
  int*   rowptr = (int*)carve((size_t)(N_NODES + 1) * 4);
  int*   col    = (int*)carve((size_t)TOT_E * 4);
  int*   bsum   = (int*)carve(256 * 4);
  int*   bofs   = (int*)carve(256 * 4);
  float* psum   = (float*)carve(128 * 128 * 4);
  float* pcnt   = (float*)carve(128 * 4);
  float* z1     = (float*)carve(128 * 512 * 4);
  float* z2     = (float*)carve(128 * 512 * 4);

  hipMemsetAsync(deg, 0, (size_t)N_NODES * 4, stream);
  hipMemsetAsync(fil, 0, (size_t)N_NODES * 4, stream);
  hipMemsetAsync(psum, 0, 128 * 128 * 4, stream);
  hipMemsetAsync(pcnt, 0, 128 * 4, stream);

  // CSR build
  int eb = (TOT_E + 255) / 256;
  count_kernel<<<eb, 256, 0, stream>>>(ei, deg);
  scanA<<<NBLK, 256, 0, stream>>>(deg, rowptr, bsum);
  scanB<<<1, 256, 0, stream>>>(bsum, bofs);
  scanC<<<NBLK, 256, 0, stream>>>(rowptr, bofs);
  fill_kernel<<<eb, 256, 0, stream>>>(ei, rowptr, fil, col);

  // 3 GAT layers: fused gemm+alpha -> fused softmax-agg
  int gemm_grid = (N_NODES + 63) / 64;
  int node_waves_grid = (N_NODES * 64 + 255) / 256;
  const float* in_ptr = x;
  for (int l = 0; l < 3; ++l) {
    gemm64<<<gemm_grid, 256, 0, stream>>>(in_ptr, W[l], As[l], Ad[l], Hb, as_, ad_, N_NODES);
    agg_kernel<<<node_waves_grid, 256, 0, stream>>>(Hb, as_, ad_, rowptr, col, B[l], hB);
    in_ptr = hB;
  }

  // mean-pool + FFN
  pool_kernel<<<(N_NODES + PCHUNK - 1) / PCHUNK, 128, 0, stream>>>(hB, bat, psum, pcnt);
  ffn1_kernel<<<NG, 512, 0, stream>>>(psum, pcnt, Wf1, bf1, z1);
  ffn2_kernel<<<NG, 512, 0, stream>>>(z1, Wf2, bf2, z2);
  ffn3_kernel<<<(NG * NCLS + 63) / 64, 64, 0, stream>>>(z2, Wf3, bf3, out);
}

// Round 4
// 313.550 us; speedup vs baseline: 2.0055x; 1.1216x over previous
//
#include <hip/hip_runtime.h>

#define N_NODES 50000
#define N_EDGES 640000
#define TOT_E (N_EDGES + N_NODES)
#define NBLK 196            // ceil(N_NODES/256)
#define NB 196              // dst buckets: dst>>8
#define BCAP 4608           // bucket capacity (mean 3520, sigma ~59)
#define EPW 4096            // edges per workgroup in scatter
#define NG 128
#define NCLS 10
#define NEG 0.2f
#define PCHUNK 50

typedef unsigned int u32;
typedef unsigned short u16;

__device__ inline u32 bf16rne(float f) {
  u32 u = __float_as_uint(f);
  return (u + 0x7FFFu + ((u >> 16) & 1u)) >> 16;
}

// ---------------- bucketed CSR build (XCD-local writes) ----------------
// phase 1: workgroup-aggregated scatter into dst-range buckets.
__global__ __launch_bounds__(256) void scatter_kernel(const int* __restrict__ ei,
                                                      int* __restrict__ bcur,
                                                      u32* __restrict__ ebuf) {
  __shared__ int hist[NB], basee[NB], lcur[NB];
  int t = threadIdx.x;
  for (int b = t; b < NB; b += 256) hist[b] = 0;
  __syncthreads();
  int e0 = blockIdx.x * EPW;
  int e1 = min(TOT_E, e0 + EPW);
  for (int e = e0 + t; e < e1; e += 256) {
    int d = (e < N_EDGES) ? ei[N_EDGES + e] : (e - N_EDGES);
    atomicAdd(&hist[d >> 8], 1);
  }
  __syncthreads();
  for (int b = t; b < NB; b += 256) {
    int c = hist[b];
    basee[b] = (c > 0) ? atomicAdd(&bcur[b], c) : 0;
    lcur[b] = 0;
  }
  __syncthreads();
  for (int e = e0 + t; e < e1; e += 256) {
    int d, s;
    if (e < N_EDGES) { d = ei[N_EDGES + e]; s = ei[e]; }
    else { d = e - N_EDGES; s = d; }
    int b = d >> 8;
    int r = basee[b] + atomicAdd(&lcur[b], 1);
    if (r < BCAP) ebuf[(size_t)b * BCAP + r] = ((u32)d << 16) | (u32)s;
  }
}

// phase 2a: per-bucket degree count (one wg per bucket, LDS counters)
__global__ __launch_bounds__(256) void deg_kernel(const int* __restrict__ bcur,
                                                  const u32* __restrict__ ebuf,
                                                  int* __restrict__ deg) {
  __shared__ int cnt[256];
  int b = blockIdx.x, t = threadIdx.x;
  cnt[t] = 0; __syncthreads();
  int n = min(bcur[b], BCAP);
  const u32* eb = ebuf + (size_t)b * BCAP;
  for (int i = t; i < n; i += 256) {
    u32 p = eb[i];
    atomicAdd(&cnt[(p >> 16) & 255], 1);
  }
  __syncthreads();
  int node = (b << 8) + t;
  if (node < N_NODES) deg[node] = cnt[t];
}

// phase 2b: scan (deg -> rowptr)
__global__ void scanA(const int* __restrict__ deg, int* __restrict__ rowptr,
                      int* __restrict__ bsum) {
  __shared__ int s[256];
  int t = threadIdx.x;
  int i = blockIdx.x * 256 + t;
  int v = (i < N_NODES) ? deg[i] : 0;
  s[t] = v; __syncthreads();
  for (int off = 1; off < 256; off <<= 1) {
    int tmp = (t >= off) ? s[t - off] : 0;
    __syncthreads();
    s[t] += tmp;
    __syncthreads();
  }
  if (i < N_NODES) rowptr[i] = s[t] - v;
  if (t == 255) bsum[blockIdx.x] = s[255];
}

__global__ void scanB(const int* __restrict__ bsum, int* __restrict__ bofs) {
  __shared__ int s[256];
  int t = threadIdx.x;
  int v = (t < NBLK) ? bsum[t] : 0;
  s[t] = v; __syncthreads();
  for (int off = 1; off < 256; off <<= 1) {
    int tmp = (t >= off) ? s[t - off] : 0;
    __syncthreads();
    s[t] += tmp;
    __syncthreads();
  }
  if (t < NBLK) bofs[t] = s[t] - v;
}

__global__ void scanC(int* __restrict__ rowptr, const int* __restrict__ bofs) {
  int i = blockIdx.x * 256 + threadIdx.x;
  if (i < N_NODES) rowptr[i] += bofs[i >> 8];
  if (i == 0) rowptr[N_NODES] = TOT_E;
}

// phase 2c: per-bucket CSR fill (one wg per bucket, LDS cursors, u16 col)
__global__ __launch_bounds__(256) void fill2_kernel(const int* __restrict__ bcur,
                                                    const u32* __restrict__ ebuf,
                                                    const int* __restrict__ rowptr,
                                                    u16* __restrict__ col) {
  __shared__ int cur[256];
  int b = blockIdx.x, t = threadIdx.x;
  int node = (b << 8) + t;
  cur[t] = (node < N_NODES) ? rowptr[node] : 0;
  __syncthreads();
  int n = min(bcur[b], BCAP);
  const u32* eb = ebuf + (size_t)b * BCAP;
  for (int i = t; i < n; i += 256) {
    u32 p = eb[i];
    int pos = atomicAdd(&cur[(p >> 16) & 255], 1);
    col[pos] = (u16)(p & 0xFFFFu);
  }
}

// ---------------- GEMM + fused alpha + bf16 pack ----------------
__global__ __launch_bounds__(256) void gemm64(const float* __restrict__ X,
                                              const float* __restrict__ W,
                                              const float* __restrict__ avs,
                                              const float* __restrict__ avd,
                                              u16* __restrict__ Hb,
                                              float* __restrict__ as_out,
                                              float* __restrict__ ad_out,
                                              int nrows) {
  __shared__ float xs[64][68];
  __shared__ float ws[64 * 128];
  int t = threadIdx.x;
  int bm0 = blockIdx.x * 64;
  int cg = t & 15, rg = t >> 4;
  float acc[4][8];
#pragma unroll
  for (int i = 0; i < 4; i++)
#pragma unroll
    for (int j = 0; j < 8; j++) acc[i][j] = 0.f;

  for (int k0 = 0; k0 < 128; k0 += 64) {
    __syncthreads();
#pragma unroll
    for (int q = 0; q < 4; ++q) {
      int lin4 = q * 256 + t;
      int r = lin4 >> 4;
      int kk = (lin4 & 15) << 2;
      float4 v = make_float4(0.f, 0.f, 0.f, 0.f);
      int row = bm0 + r;
      if (row < nrows) v = *(const float4*)(X + (size_t)row * 128 + k0 + kk);
      *(float4*)&xs[r][kk] = v;
    }
#pragma unroll
    for (int q = 0; q < 8; ++q) {
      int lin4 = q * 256 + t;
      float4 v = *(const float4*)(W + (size_t)k0 * 128 + (size_t)lin4 * 4);
      *(float4*)&ws[lin4 * 4] = v;
    }
    __syncthreads();
    for (int kk = 0; kk < 64; ++kk) {
      float xv[4];
#pragma unroll
      for (int i = 0; i < 4; i++) xv[i] = xs[rg * 4 + i][kk];
      float4 w0 = *(const float4*)&ws[kk * 128 + cg * 8];
      float4 w1 = *(const float4*)&ws[kk * 128 + cg * 8 + 4];
      float wv[8] = {w0.x, w0.y, w0.z, w0.w, w1.x, w1.y, w1.z, w1.w};
#pragma unroll
      for (int i = 0; i < 4; i++)
#pragma unroll
        for (int j = 0; j < 8; j++) acc[i][j] = fmaf(xv[i], wv[j], acc[i][j]);
    }
  }

  float as_v[8], ad_v[8];
#pragma unroll
  for (int j = 0; j < 8; j++) {
    as_v[j] = avs[cg * 8 + j];
    ad_v[j] = avd[cg * 8 + j];
  }
#pragma unroll
  for (int i = 0; i < 4; i++) {
    int row = bm0 + rg * 4 + i;
    if (row < nrows) {
      float ps = 0.f, pd = 0.f;
#pragma unroll
      for (int j = 0; j < 8; j++) {
        ps = fmaf(acc[i][j], as_v[j], ps);
        pd = fmaf(acc[i][j], ad_v[j], pd);
      }
#pragma unroll
      for (int off = 8; off; off >>= 1) {
        ps += __shfl_xor(ps, off, 64);
        pd += __shfl_xor(pd, off, 64);
      }
      if (cg == 0) { as_out[row] = ps; ad_out[row] = pd; }
      u32 p0 = bf16rne(acc[i][0]) | (bf16rne(acc[i][1]) << 16);
      u32 p1 = bf16rne(acc[i][2]) | (bf16rne(acc[i][3]) << 16);
      u32 p2 = bf16rne(acc[i][4]) | (bf16rne(acc[i][5]) << 16);
      u32 p3 = bf16rne(acc[i][6]) | (bf16rne(acc[i][7]) << 16);
      uint4 st = make_uint4(p0, p1, p2, p3);
      *(uint4*)(Hb + (size_t)row * 128 + cg * 8) = st;
    }
  }
}

// ---------------- fused segment-softmax + aggregation + bias + relu ----------------
__global__ __launch_bounds__(256) void agg_kernel(
    const u16* __restrict__ Hb, const float* __restrict__ asv,
    const float* __restrict__ adv, const int* __restrict__ rowptr,
    const u16* __restrict__ col, const float* __restrict__ bias,
    float* __restrict__ O) {
  int gid = blockIdx.x * blockDim.x + threadIdx.x;
  int node = gid >> 6;
  if (node >= N_NODES) return;
  int lane = threadIdx.x & 63;
  int q = lane >> 4;
  int li = lane & 15;
  int r0 = rowptr[node], r1 = rowptr[node + 1];
  float ad = adv[node];
  float acc[8];
#pragma unroll
  for (int k = 0; k < 8; k++) acc[k] = 0.f;
  float den = 0.f;

  for (int base = r0; base < r1; base += 64) {
    int cnt = min(64, r1 - base);
    int s_l = 0; float ex_l = 0.f;
    if (lane < cnt) {
      s_l = (int)col[base + lane];
      float tt = asv[s_l] + ad;
      tt = (tt > 0.f) ? tt : NEG * tt;
      ex_l = __expf(tt);
    }
    float d = ex_l;
#pragma unroll
    for (int off = 32; off; off >>= 1) d += __shfl_xor(d, off, 64);
    den += d;

    int j = 0;
    for (; j + 8 <= cnt; j += 8) {
      int i0 = j + q, i1 = j + 4 + q;
      int s0 = __shfl(s_l, i0, 64); float e0 = __shfl(ex_l, i0, 64);
      int s1 = __shfl(s_l, i1, 64); float e1 = __shfl(ex_l, i1, 64);
      uint4 h0 = *(const uint4*)(Hb + (size_t)s0 * 128 + li * 8);
      uint4 h1 = *(const uint4*)(Hb + (size_t)s1 * 128 + li * 8);
      u32 w0[4] = {h0.x, h0.y, h0.z, h0.w};
      u32 w1[4] = {h1.x, h1.y, h1.z, h1.w};
#pragma unroll
      for (int k = 0; k < 4; k++) {
        acc[2*k]   = fmaf(e0, __uint_as_float(w0[k] << 16), acc[2*k]);
        acc[2*k+1] = fmaf(e0, __uint_as_float(w0[k] & 0xFFFF0000u), acc[2*k+1]);
      }
#pragma unroll
      for (int k = 0; k < 4; k++) {
        acc[2*k]   = fmaf(e1, __uint_as_float(w1[k] << 16), acc[2*k]);
        acc[2*k+1] = fmaf(e1, __uint_as_float(w1[k] & 0xFFFF0000u), acc[2*k+1]);
      }
    }
    for (; j < cnt; j += 4) {
      int i0 = j + q;
      int s0 = __shfl(s_l, i0, 64); float e0 = __shfl(ex_l, i0, 64);
      if (i0 < cnt) {
        uint4 h0 = *(const uint4*)(Hb + (size_t)s0 * 128 + li * 8);
        u32 w0[4] = {h0.x, h0.y, h0.z, h0.w};
#pragma unroll
        for (int k = 0; k < 4; k++) {
          acc[2*k]   = fmaf(e0, __uint_as_float(w0[k] << 16), acc[2*k]);
          acc[2*k+1] = fmaf(e0, __uint_as_float(w0[k] & 0xFFFF0000u), acc[2*k+1]);
        }
      }
    }
  }
#pragma unroll
  for (int k = 0; k < 8; k++) {
    acc[k] += __shfl_xor(acc[k], 16, 64);
    acc[k] += __shfl_xor(acc[k], 32, 64);
  }

  if (q == 0) {
    float inv = 1.f / (den + 1e-16f);
    float4 b0 = *(const float4*)(bias + li * 8);
    float4 b1 = *(const float4*)(bias + li * 8 + 4);
    float4 o0, o1;
    o0.x = fmaxf(fmaf(acc[0], inv, b0.x), 0.f);
    o0.y = fmaxf(fmaf(acc[1], inv, b0.y), 0.f);
    o0.z = fmaxf(fmaf(acc[2], inv, b0.z), 0.f);
    o0.w = fmaxf(fmaf(acc[3], inv, b0.w), 0.f);
    o1.x = fmaxf(fmaf(acc[4], inv, b1.x), 0.f);
    o1.y = fmaxf(fmaf(acc[5], inv, b1.y), 0.f);
    o1.z = fmaxf(fmaf(acc[6], inv, b1.z), 0.f);
    o1.w = fmaxf(fmaf(acc[7], inv, b1.w), 0.f);
    *(float4*)(O + (size_t)node * 128 + li * 8) = o0;
    *(float4*)(O + (size_t)node * 128 + li * 8 + 4) = o1;
  }
}

// ---------------- pooling (batch is sorted) ----------------
__global__ void pool_kernel(const float* __restrict__ H, const int* __restrict__ batch,
                            float* __restrict__ psum, float* __restrict__ pcnt) {
  int t = threadIdx.x;  // 128
  int start = blockIdx.x * PCHUNK;
  int end = min(N_NODES, start + PCHUNK);
  if (start >= end) return;
  int cur = batch[start];
  float acc = 0.f; int cnt = 0;
  for (int i = start; i < end; ++i) {
    int g = batch[i];
    if (g != cur) {
      atomicAdd(&psum[cur * 128 + t], acc);
      if (t == 0) atomicAdd(&pcnt[cur], (float)cnt);
      acc = 0.f; cnt = 0; cur = g;
    }
    acc += H[(size_t)i * 128 + t];
    cnt++;
  }
  atomicAdd(&psum[cur * 128 + t], acc);
  if (t == 0) atomicAdd(&pcnt[cur], (float)cnt);
}

// ---------------- FFN head ----------------
__global__ void ffn1_kernel(const float* __restrict__ psum, const float* __restrict__ pcnt,
                            const float* __restrict__ Wf1, const float* __restrict__ bf1,
                            float* __restrict__ z1) {
  __shared__ float prow[128];
  int g = blockIdx.x, t = threadIdx.x;  // 512
  if (t < 128) prow[t] = psum[g * 128 + t] / fmaxf(pcnt[g], 1.f);
  __syncthreads();
  float acc = bf1[t];
  for (int k = 0; k < 128; ++k) acc = fmaf(prow[k], Wf1[k * 512 + t], acc);
  z1[g * 512 + t] = fmaxf(acc, 0.f);
}

__global__ void ffn2_kernel(const float* __restrict__ z1, const float* __restrict__ Wf2,
                            const float* __restrict__ bf2, float* __restrict__ z2) {
  __shared__ float zrow[512];
  int g = blockIdx.x, t = threadIdx.x;  // 512
  zrow[t] = z1[g * 512 + t];
  __syncthreads();
  float acc = bf2[t];
  for (int k = 0; k < 512; ++k) acc = fmaf(zrow[k], Wf2[k * 512 + t], acc);
  z2[g * 512 + t] = fmaxf(acc, 0.f);
}

__global__ void ffn3_kernel(const float* __restrict__ z2, const float* __restrict__ Wf3,
                            const float* __restrict__ bf3, float* __restrict__ out) {
  int gid = blockIdx.x * blockDim.x + threadIdx.x;
  if (gid >= NG * NCLS) return;
  int g = gid / NCLS, c = gid % NCLS;
  float acc = bf3[c];
  const float* z = z2 + (size_t)g * 512;
  for (int k = 0; k < 512; ++k) acc = fmaf(z[k], Wf3[k * NCLS + c], acc);
  out[gid] = acc;
}

extern "C" void kernel_launch(void* const* d_in, const int* in_sizes, int n_in,
                              void* d_out, int out_size, void* d_ws, size_t ws_size,
                              hipStream_t stream) {
  const float* x   = (const float*)d_in[0];
  const int*   ei  = (const int*)d_in[1];
  const int*   bat = (const int*)d_in[2];
  const float* W[3]  = {(const float*)d_in[3], (const float*)d_in[7],  (const float*)d_in[11]};
  const float* As[3] = {(const float*)d_in[4], (const float*)d_in[8],  (const float*)d_in[12]};
  const float* Ad[3] = {(const float*)d_in[5], (const float*)d_in[9],  (const float*)d_in[13]};
  const float* B[3]  = {(const float*)d_in[6], (const float*)d_in[10], (const float*)d_in[14]};
  const float* Wf1 = (const float*)d_in[15]; const float* bf1 = (const float*)d_in[16];
  const float* Wf2 = (const float*)d_in[17]; const float* bf2 = (const float*)d_in[18];
  const float* Wf3 = (const float*)d_in[19]; const float* bf3 = (const float*)d_in[20];
  float* out = (float*)d_out;

  size_t off = 0;
  auto carve = [&](size_t bytes) {
    void* p = (char*)d_ws + off;
    off += (bytes + 255) & ~(size_t)255;
    return p;
  };
  u16*   Hb     = (u16*)carve((size_t)N_NODES * 128 * 2);
  float* hB     = (float*)carve((size_t)N_NODES * 128 * 4);
  float* as_    = (float*)carve((size_t)N_NODES * 4);
  float* ad_    = (float*)carve((size_t)N_NODES * 4);
  int*   deg    = (int*)carve((size_t)N_NODES * 4);
  int*   rowptr = (int*)carve((size_t)(N_NODES + 1) * 4);
  u16*   col    = (u16*)carve((size_t)TOT_E * 2);
  u32*   ebuf   = (u32*)carve((size_t)NB * BCAP * 4);
  int*   bcur   = (int*)carve(NB * 4);
  int*   bsum   = (int*)carve(256 * 4);
  int*   bofs   = (int*)carve(256 * 4);
  float* psum   = (float*)carve(128 * 128 * 4);
  float* pcnt   = (float*)carve(128 * 4);
  float* z1     = (float*)carve(128 * 512 * 4);
  float* z2     = (float*)carve(128 * 512 * 4);

  hipMemsetAsync(bcur, 0, NB * 4, stream);
  hipMemsetAsync(psum, 0, 128 * 128 * 4, stream);
  hipMemsetAsync(pcnt, 0, 128 * 4, stream);

  // bucketed CSR build
  int sgrid = (TOT_E + EPW - 1) / EPW;
  scatter_kernel<<<sgrid, 256, 0, stream>>>(ei, bcur, ebuf);
  deg_kernel<<<NB, 256, 0, stream>>>(bcur, ebuf, deg);
  scanA<<<NBLK, 256, 0, stream>>>(deg, rowptr, bsum);
  scanB<<<1, 256, 0, stream>>>(bsum, bofs);
  scanC<<<NBLK, 256, 0, stream>>>(rowptr, bofs);
  fill2_kernel<<<NB, 256, 0, stream>>>(bcur, ebuf, rowptr, col);

  // 3 GAT layers: fused gemm+alpha -> fused softmax-agg
  int gemm_grid = (N_NODES + 63) / 64;
  int node_waves_grid = (N_NODES * 64 + 255) / 256;
  const float* in_ptr = x;
  for (int l = 0; l < 3; ++l) {
    gemm64<<<gemm_grid, 256, 0, stream>>>(in_ptr, W[l], As[l], Ad[l], Hb, as_, ad_, N_NODES);
    agg_kernel<<<node_waves_grid, 256, 0, stream>>>(Hb, as_, ad_, rowptr, col, B[l], hB);
    in_ptr = hB;
  }

  // mean-pool + FFN
  pool_kernel<<<(N_NODES + PCHUNK - 1) / PCHUNK, 128, 0, stream>>>(hB, bat, psum, pcnt);
  ffn1_kernel<<<NG, 512, 0, stream>>>(psum, pcnt, Wf1, bf1, z1);
  ffn2_kernel<<<NG, 512, 0, stream>>>(z1, Wf2, bf2, z2);
  ffn3_kernel<<<(NG * NCLS + 63) / 64, 64, 0, stream>>>(z2, Wf3, bf3, out);
}

// Round 5
// 270.232 us; speedup vs baseline: 2.3270x; 1.1603x over previous
//
#include <hip/hip_runtime.h>

#define N_NODES 50000
#define N_EDGES 640000
#define TOT_E (N_EDGES + N_NODES)
#define NBLK 196            // ceil(N_NODES/256)
#define NB 196              // dst buckets: dst>>8
#define BCAP 4608           // bucket capacity (mean 3520)
#define EPW 4096            // edges per workgroup in scatter
#define NG 128
#define NCLS 10
#define NEG 0.2f
#define PCHUNK 50

typedef unsigned int u32;
typedef unsigned short u16;
typedef __attribute__((ext_vector_type(8))) short s16x8;
typedef __attribute__((ext_vector_type(4))) float f32x4;

__device__ inline u32 bf16rne(float f) {
  u32 u = __float_as_uint(f);
  return (u + 0x7FFFu + ((u >> 16) & 1u)) >> 16;
}
__device__ inline float bf2f(u16 v) { return __uint_as_float((u32)v << 16); }

// ---------------- init (replaces expensive tiny memsets) ----------------
__global__ void init_kernel(int* __restrict__ bcur, float* __restrict__ psum,
                            float* __restrict__ pcnt) {
  int i = blockIdx.x * 256 + threadIdx.x;
  if (i < NB) bcur[i] = 0;
  if (i < 128 * 128) psum[i] = 0.f;
  if (i < 128) pcnt[i] = 0.f;
}

// ---------------- input/weight bf16 prep ----------------
__global__ __launch_bounds__(256) void xconv_kernel(const float* __restrict__ x,
                                                    u16* __restrict__ Xb) {
  int i = blockIdx.x * 256 + threadIdx.x;    // one uint4 (8 floats) per thread
  const float4* x4 = (const float4*)x;
  float4 f0 = x4[i * 2], f1 = x4[i * 2 + 1];
  uint4 pb;
  pb.x = bf16rne(f0.x) | (bf16rne(f0.y) << 16);
  pb.y = bf16rne(f0.z) | (bf16rne(f0.w) << 16);
  pb.z = bf16rne(f1.x) | (bf16rne(f1.y) << 16);
  pb.w = bf16rne(f1.z) | (bf16rne(f1.w) << 16);
  ((uint4*)Xb)[i] = pb;
}

// Wt[l][col][k] = bf16(W_l[k][col])   (transposed, bf16)
__global__ void wprep_kernel(const float* __restrict__ W0, const float* __restrict__ W1,
                             const float* __restrict__ W2, u16* __restrict__ Wt) {
  int b = blockIdx.x;            // 0..383
  int l = b >> 7, c = b & 127;
  int k = threadIdx.x;           // 128
  const float* W = (l == 0) ? W0 : ((l == 1) ? W1 : W2);
  Wt[((size_t)l << 14) + c * 128 + k] = (u16)bf16rne(W[k * 128 + c]);
}

// ---------------- bucketed CSR build (XCD-local writes) ----------------
__global__ __launch_bounds__(256) void scatter_kernel(const int* __restrict__ ei,
                                                      int* __restrict__ bcur,
                                                      u32* __restrict__ ebuf) {
  __shared__ int hist[NB], basee[NB], lcur[NB];
  int t = threadIdx.x;
  for (int b = t; b < NB; b += 256) hist[b] = 0;
  __syncthreads();
  int e0 = blockIdx.x * EPW;
  int e1 = min(TOT_E, e0 + EPW);
  for (int e = e0 + t; e < e1; e += 256) {
    int d = (e < N_EDGES) ? ei[N_EDGES + e] : (e - N_EDGES);
    atomicAdd(&hist[d >> 8], 1);
  }
  __syncthreads();
  for (int b = t; b < NB; b += 256) {
    int c = hist[b];
    basee[b] = (c > 0) ? atomicAdd(&bcur[b], c) : 0;
    lcur[b] = 0;
  }
  __syncthreads();
  for (int e = e0 + t; e < e1; e += 256) {
    int d, s;
    if (e < N_EDGES) { d = ei[N_EDGES + e]; s = ei[e]; }
    else { d = e - N_EDGES; s = d; }
    int b = d >> 8;
    int r = basee[b] + atomicAdd(&lcur[b], 1);
    if (r < BCAP) ebuf[(size_t)b * BCAP + r] = ((u32)d << 16) | (u32)s;
  }
}

__global__ __launch_bounds__(256) void deg_kernel(const int* __restrict__ bcur,
                                                  const u32* __restrict__ ebuf,
                                                  int* __restrict__ deg) {
  __shared__ int cnt[256];
  int b = blockIdx.x, t = threadIdx.x;
  cnt[t] = 0; __syncthreads();
  int n = min(bcur[b], BCAP);
  const u32* eb = ebuf + (size_t)b * BCAP;
  for (int i = t; i < n; i += 256) {
    u32 p = eb[i];
    atomicAdd(&cnt[(p >> 16) & 255], 1);
  }
  __syncthreads();
  int node = (b << 8) + t;
  if (node < N_NODES) deg[node] = cnt[t];
}

__global__ void scanA(const int* __restrict__ deg, int* __restrict__ rowptr,
                      int* __restrict__ bsum) {
  __shared__ int s[256];
  int t = threadIdx.x;
  int i = blockIdx.x * 256 + t;
  int v = (i < N_NODES) ? deg[i] : 0;
  s[t] = v; __syncthreads();
  for (int off = 1; off < 256; off <<= 1) {
    int tmp = (t >= off) ? s[t - off] : 0;
    __syncthreads();
    s[t] += tmp;
    __syncthreads();
  }
  if (i < N_NODES) rowptr[i] = s[t] - v;
  if (t == 255) bsum[blockIdx.x] = s[255];
}

__global__ void scanB(const int* __restrict__ bsum, int* __restrict__ bofs) {
  __shared__ int s[256];
  int t = threadIdx.x;
  int v = (t < NBLK) ? bsum[t] : 0;
  s[t] = v; __syncthreads();
  for (int off = 1; off < 256; off <<= 1) {
    int tmp = (t >= off) ? s[t - off] : 0;
    __syncthreads();
    s[t] += tmp;
    __syncthreads();
  }
  if (t < NBLK) bofs[t] = s[t] - v;
}

__global__ void scanC(int* __restrict__ rowptr, const int* __restrict__ bofs) {
  int i = blockIdx.x * 256 + threadIdx.x;
  if (i < N_NODES) rowptr[i] += bofs[i >> 8];
  if (i == 0) rowptr[N_NODES] = TOT_E;
}

__global__ __launch_bounds__(256) void fill2_kernel(const int* __restrict__ bcur,
                                                    const u32* __restrict__ ebuf,
                                                    const int* __restrict__ rowptr,
                                                    u16* __restrict__ col) {
  __shared__ int cur[256];
  int b = blockIdx.x, t = threadIdx.x;
  int node = (b << 8) + t;
  cur[t] = (node < N_NODES) ? rowptr[node] : 0;
  __syncthreads();
  int n = min(bcur[b], BCAP);
  const u32* eb = ebuf + (size_t)b * BCAP;
  for (int i = t; i < n; i += 256) {
    u32 p = eb[i];
    int pos = atomicAdd(&cur[(p >> 16) & 255], 1);
    col[pos] = (u16)(p & 0xFFFFu);
  }
}

// ---------------- MFMA GEMM: Hb[m,128] = bf16( Xb[m,128] @ W ) + fused alpha ----------------
// one wave per 16-row tile. A-frag: lane&15=row, k=8*(lane>>4)+j (contiguous dwordx4 from Xb).
// B-frag from transposed Wt[col][k]. D: col=lane&15, row=(lane>>4)*4+reg (m89-verified).
__global__ __launch_bounds__(64) void gemm_mfma(const u16* __restrict__ Xb,
                                                const u16* __restrict__ Wt,
                                                const float* __restrict__ avs,
                                                const float* __restrict__ avd,
                                                u16* __restrict__ Hb,
                                                float* __restrict__ as_out,
                                                float* __restrict__ ad_out) {
  __shared__ u16 st[16 * 128];
  int lane = threadIdx.x;
  int m0 = blockIdx.x * 16;
  int ar = lane & 15, kg = lane >> 4;
  const u16* xrow = Xb + (size_t)(m0 + ar) * 128 + kg * 8;
  f32x4 acc[8];
#pragma unroll
  for (int n = 0; n < 8; n++) acc[n] = (f32x4){0.f, 0.f, 0.f, 0.f};
#pragma unroll
  for (int ks = 0; ks < 4; ks++) {
    s16x8 a = *(const s16x8*)(xrow + ks * 32);
#pragma unroll
    for (int n = 0; n < 8; n++) {
      s16x8 b = *(const s16x8*)(Wt + (size_t)(n * 16 + ar) * 128 + ks * 32 + kg * 8);
      acc[n] = __builtin_amdgcn_mfma_f32_16x16x32_bf16(a, b, acc[n], 0, 0, 0);
    }
  }
  // fused alpha on fp32 accumulators
  float avsv[8], advv[8];
#pragma unroll
  for (int n = 0; n < 8; n++) { avsv[n] = avs[n * 16 + ar]; advv[n] = avd[n * 16 + ar]; }
#pragma unroll
  for (int reg = 0; reg < 4; reg++) {
    float ps = 0.f, pd = 0.f;
#pragma unroll
    for (int n = 0; n < 8; n++) {
      ps = fmaf(acc[n][reg], avsv[n], ps);
      pd = fmaf(acc[n][reg], advv[n], pd);
    }
#pragma unroll
    for (int off = 1; off < 16; off <<= 1) {
      ps += __shfl_xor(ps, off, 64);
      pd += __shfl_xor(pd, off, 64);
    }
    if (ar == 0) {
      int row = m0 + kg * 4 + reg;
      as_out[row] = ps; ad_out[row] = pd;
    }
  }
  // bf16 store via LDS repack (scattered cols -> coalesced uint4)
#pragma unroll
  for (int n = 0; n < 8; n++)
#pragma unroll
    for (int reg = 0; reg < 4; reg++)
      st[(kg * 4 + reg) * 128 + n * 16 + ar] = (u16)bf16rne(acc[n][reg]);
  __syncthreads();
#pragma unroll
  for (int i = 0; i < 4; i++) {
    int u4 = i * 64 + lane;
    int r = u4 >> 4;
    int c8 = (u4 & 15) * 8;
    *(uint4*)(Hb + (size_t)(m0 + r) * 128 + c8) = *(const uint4*)&st[r * 128 + c8];
  }
}

// ---------------- fused segment-softmax + aggregation + bias + relu (bf16 out) ----------------
__global__ __launch_bounds__(256) void agg_kernel(
    const u16* __restrict__ Hb, const float* __restrict__ asv,
    const float* __restrict__ adv, const int* __restrict__ rowptr,
    const u16* __restrict__ col, const float* __restrict__ bias,
    u16* __restrict__ Ob) {
  int gid = blockIdx.x * blockDim.x + threadIdx.x;
  int node = gid >> 6;
  if (node >= N_NODES) return;
  int lane = threadIdx.x & 63;
  int q = lane >> 4;
  int li = lane & 15;
  int r0 = rowptr[node], r1 = rowptr[node + 1];
  float ad = adv[node];
  float acc[8];
#pragma unroll
  for (int k = 0; k < 8; k++) acc[k] = 0.f;
  float den = 0.f;

  for (int base = r0; base < r1; base += 64) {
    int cnt = min(64, r1 - base);
    int s_l = 0; float ex_l = 0.f;
    if (lane < cnt) {
      s_l = (int)col[base + lane];
      float tt = asv[s_l] + ad;
      tt = (tt > 0.f) ? tt : NEG * tt;
      ex_l = __expf(tt);
    }
    float d = ex_l;
#pragma unroll
    for (int off = 32; off; off >>= 1) d += __shfl_xor(d, off, 64);
    den += d;

    int j = 0;
    for (; j + 8 <= cnt; j += 8) {
      int i0 = j + q, i1 = j + 4 + q;
      int s0 = __shfl(s_l, i0, 64); float e0 = __shfl(ex_l, i0, 64);
      int s1 = __shfl(s_l, i1, 64); float e1 = __shfl(ex_l, i1, 64);
      uint4 h0 = *(const uint4*)(Hb + (size_t)s0 * 128 + li * 8);
      uint4 h1 = *(const uint4*)(Hb + (size_t)s1 * 128 + li * 8);
      u32 w0[4] = {h0.x, h0.y, h0.z, h0.w};
      u32 w1[4] = {h1.x, h1.y, h1.z, h1.w};
#pragma unroll
      for (int k = 0; k < 4; k++) {
        acc[2 * k]     = fmaf(e0, __uint_as_float(w0[k] << 16), acc[2 * k]);
        acc[2 * k + 1] = fmaf(e0, __uint_as_float(w0[k] & 0xFFFF0000u), acc[2 * k + 1]);
      }
#pragma unroll
      for (int k = 0; k < 4; k++) {
        acc[2 * k]     = fmaf(e1, __uint_as_float(w1[k] << 16), acc[2 * k]);
        acc[2 * k + 1] = fmaf(e1, __uint_as_float(w1[k] & 0xFFFF0000u), acc[2 * k + 1]);
      }
    }
    for (; j < cnt; j += 4) {
      int i0 = j + q;
      int s0 = __shfl(s_l, i0, 64); float e0 = __shfl(ex_l, i0, 64);
      if (i0 < cnt) {
        uint4 h0 = *(const uint4*)(Hb + (size_t)s0 * 128 + li * 8);
        u32 w0[4] = {h0.x, h0.y, h0.z, h0.w};
#pragma unroll
        for (int k = 0; k < 4; k++) {
          acc[2 * k]     = fmaf(e0, __uint_as_float(w0[k] << 16), acc[2 * k]);
          acc[2 * k + 1] = fmaf(e0, __uint_as_float(w0[k] & 0xFFFF0000u), acc[2 * k + 1]);
        }
      }
    }
  }
#pragma unroll
  for (int k = 0; k < 8; k++) {
    acc[k] += __shfl_xor(acc[k], 16, 64);
    acc[k] += __shfl_xor(acc[k], 32, 64);
  }

  if (q == 0) {
    float inv = 1.f / (den + 1e-16f);
    float4 b0 = *(const float4*)(bias + li * 8);
    float4 b1 = *(const float4*)(bias + li * 8 + 4);
    float o[8];
    o[0] = fmaxf(fmaf(acc[0], inv, b0.x), 0.f);
    o[1] = fmaxf(fmaf(acc[1], inv, b0.y), 0.f);
    o[2] = fmaxf(fmaf(acc[2], inv, b0.z), 0.f);
    o[3] = fmaxf(fmaf(acc[3], inv, b0.w), 0.f);
    o[4] = fmaxf(fmaf(acc[4], inv, b1.x), 0.f);
    o[5] = fmaxf(fmaf(acc[5], inv, b1.y), 0.f);
    o[6] = fmaxf(fmaf(acc[6], inv, b1.z), 0.f);
    o[7] = fmaxf(fmaf(acc[7], inv, b1.w), 0.f);
    uint4 pb;
    pb.x = bf16rne(o[0]) | (bf16rne(o[1]) << 16);
    pb.y = bf16rne(o[2]) | (bf16rne(o[3]) << 16);
    pb.z = bf16rne(o[4]) | (bf16rne(o[5]) << 16);
    pb.w = bf16rne(o[6]) | (bf16rne(o[7]) << 16);
    *(uint4*)(Ob + (size_t)node * 128 + li * 8) = pb;
  }
}

// ---------------- pooling (batch is sorted; bf16 input) ----------------
__global__ void pool_kernel(const u16* __restrict__ Hb, const int* __restrict__ batch,
                            float* __restrict__ psum, float* __restrict__ pcnt) {
  int t = threadIdx.x;  // 128
  int start = blockIdx.x * PCHUNK;
  int end = min(N_NODES, start + PCHUNK);
  if (start >= end) return;
  int cur = batch[start];
  float acc = 0.f; int cnt = 0;
  for (int i = start; i < end; ++i) {
    int g = batch[i];
    if (g != cur) {
      atomicAdd(&psum[cur * 128 + t], acc);
      if (t == 0) atomicAdd(&pcnt[cur], (float)cnt);
      acc = 0.f; cnt = 0; cur = g;
    }
    acc += bf2f(Hb[(size_t)i * 128 + t]);
    cnt++;
  }
  atomicAdd(&psum[cur * 128 + t], acc);
  if (t == 0) atomicAdd(&pcnt[cur], (float)cnt);
}

// ---------------- FFN head ----------------
__global__ void ffn1_kernel(const float* __restrict__ psum, const float* __restrict__ pcnt,
                            const float* __restrict__ Wf1, const float* __restrict__ bf1,
                            float* __restrict__ z1) {
  __shared__ float prow[128];
  int g = blockIdx.x, t = threadIdx.x;  // 512
  if (t < 128) prow[t] = psum[g * 128 + t] / fmaxf(pcnt[g], 1.f);
  __syncthreads();
  float acc = bf1[t];
  for (int k = 0; k < 128; ++k) acc = fmaf(prow[k], Wf1[k * 512 + t], acc);
  z1[g * 512 + t] = fmaxf(acc, 0.f);
}

__global__ void ffn2_kernel(const float* __restrict__ z1, const float* __restrict__ Wf2,
                            const float* __restrict__ bf2, float* __restrict__ z2) {
  __shared__ float zrow[512];
  int g = blockIdx.x, t = threadIdx.x;  // 512
  zrow[t] = z1[g * 512 + t];
  __syncthreads();
  float acc = bf2[t];
  for (int k = 0; k < 512; ++k) acc = fmaf(zrow[k], Wf2[k * 512 + t], acc);
  z2[g * 512 + t] = fmaxf(acc, 0.f);
}

__global__ void ffn3_kernel(const float* __restrict__ z2, const float* __restrict__ Wf3,
                            const float* __restrict__ bf3, float* __restrict__ out) {
  int gid = blockIdx.x * blockDim.x + threadIdx.x;
  if (gid >= NG * NCLS) return;
  int g = gid / NCLS, c = gid % NCLS;
  float acc = bf3[c];
  const float* z = z2 + (size_t)g * 512;
  for (int k = 0; k < 512; ++k) acc = fmaf(z[k], Wf3[k * NCLS + c], acc);
  out[gid] = acc;
}

extern "C" void kernel_launch(void* const* d_in, const int* in_sizes, int n_in,
                              void* d_out, int out_size, void* d_ws, size_t ws_size,
                              hipStream_t stream) {
  const float* x   = (const float*)d_in[0];
  const int*   ei  = (const int*)d_in[1];
  const int*   bat = (const int*)d_in[2];
  const float* W[3]  = {(const float*)d_in[3], (const float*)d_in[7],  (const float*)d_in[11]};
  const float* As[3] = {(const float*)d_in[4], (const float*)d_in[8],  (const float*)d_in[12]};
  const float* Ad[3] = {(const float*)d_in[5], (const float*)d_in[9],  (const float*)d_in[13]};
  const float* B[3]  = {(const float*)d_in[6], (const float*)d_in[10], (const float*)d_in[14]};
  const float* Wf1 = (const float*)d_in[15]; const float* bf1 = (const float*)d_in[16];
  const float* Wf2 = (const float*)d_in[17]; const float* bf2 = (const float*)d_in[18];
  const float* Wf3 = (const float*)d_in[19]; const float* bf3 = (const float*)d_in[20];
  float* out = (float*)d_out;

  size_t off = 0;
  auto carve = [&](size_t bytes) {
    void* p = (char*)d_ws + off;
    off += (bytes + 255) & ~(size_t)255;
    return p;
  };
  u16*   Xb0    = (u16*)carve((size_t)N_NODES * 128 * 2);
  u16*   Xb1    = (u16*)carve((size_t)N_NODES * 128 * 2);
  u16*   Hb     = (u16*)carve((size_t)N_NODES * 128 * 2);
  u16*   Wt     = (u16*)carve((size_t)3 * 128 * 128 * 2);
  float* as_    = (float*)carve((size_t)N_NODES * 4);
  float* ad_    = (float*)carve((size_t)N_NODES * 4);
  int*   deg    = (int*)carve((size_t)N_NODES * 4);
  int*   rowptr = (int*)carve((size_t)(N_NODES + 1) * 4);
  u16*   col    = (u16*)carve((size_t)TOT_E * 2);
  u32*   ebuf   = (u32*)carve((size_t)NB * BCAP * 4);
  int*   bcur   = (int*)carve(NB * 4);
  int*   bsum   = (int*)carve(256 * 4);
  int*   bofs   = (int*)carve(256 * 4);
  float* psum   = (float*)carve(128 * 128 * 4);
  float* pcnt   = (float*)carve(128 * 4);
  float* z1     = (float*)carve(128 * 512 * 4);
  float* z2     = (float*)carve(128 * 512 * 4);

  // init + prep
  init_kernel<<<64, 256, 0, stream>>>(bcur, psum, pcnt);
  xconv_kernel<<<3125, 256, 0, stream>>>(x, Xb0);
  wprep_kernel<<<384, 128, 0, stream>>>(W[0], W[1], W[2], Wt);

  // bucketed CSR build
  int sgrid = (TOT_E + EPW - 1) / EPW;
  scatter_kernel<<<sgrid, 256, 0, stream>>>(ei, bcur, ebuf);
  deg_kernel<<<NB, 256, 0, stream>>>(bcur, ebuf, deg);
  scanA<<<NBLK, 256, 0, stream>>>(deg, rowptr, bsum);
  scanB<<<1, 256, 0, stream>>>(bsum, bofs);
  scanC<<<NBLK, 256, 0, stream>>>(rowptr, bofs);
  fill2_kernel<<<NB, 256, 0, stream>>>(bcur, ebuf, rowptr, col);

  // 3 GAT layers: MFMA gemm (+fused alpha) -> fused softmax-agg (bf16 out)
  int node_waves_grid = (N_NODES * 64 + 255) / 256;
  const u16* gin = Xb0;
  u16* aout = Xb1;
  for (int l = 0; l < 3; ++l) {
    gemm_mfma<<<3125, 64, 0, stream>>>(gin, Wt + (size_t)l * 16384, As[l], Ad[l],
                                       Hb, as_, ad_);
    agg_kernel<<<node_waves_grid, 256, 0, stream>>>(Hb, as_, ad_, rowptr, col, B[l], aout);
    gin = aout;
    aout = (aout == Xb1) ? Xb0 : Xb1;
  }

  // mean-pool + FFN  (gin now points at the layer-3 bf16 output)
  pool_kernel<<<(N_NODES + PCHUNK - 1) / PCHUNK, 128, 0, stream>>>(gin, bat, psum, pcnt);
  ffn1_kernel<<<NG, 512, 0, stream>>>(psum, pcnt, Wf1, bf1, z1);
  ffn2_kernel<<<NG, 512, 0, stream>>>(z1, Wf2, bf2, z2);
  ffn3_kernel<<<(NG * NCLS + 63) / 64, 64, 0, stream>>>(z2, Wf3, bf3, out);
}